// Round 6
// baseline (116.106 us; speedup 1.0000x reference)
//
#include <hip/hip_runtime.h>
#include <math.h>

// Problem constants (hardcoded in reference)
#define V 2048
#define DF 128
#define NK 73          // 1 + J + J^2 branch outputs
#define NSLICE 16      // v-slices per branch in the scatter kernel
#define A_F 0.34657359027997264f   // A = R*ln(2)/(J-R+1) = ln2/2
#define TWO_PI_F 6.283185307179586f

// Stage 1: one block per node v. deg[v] = rowsum(W), then the J=8 filter
// responses at E = deg/max(1,deg). The reference's Lmat = diag(deg)*dhalf^2
// is EXACTLY diagonal, so eigh is a signed permutation and every filter
// matrix g_j is diag(h_j(deg[v])) — the scattering is pointwise in v.
// 2048 blocks -> 8 blocks/CU: full latency hiding for the 16.8 MB W read.
// Block 0 also zeroes the last-block counters for stage 2 (ws is 0xAA-
// poisoned before every call; stream order guarantees this lands first).
__global__ __launch_bounds__(256) void k_filters(const float* __restrict__ W,
                                                 float* __restrict__ c,
                                                 int* __restrict__ cnt) {
    __shared__ float red[4];
    const int v = blockIdx.x;
    const int tid = threadIdx.x;
    if (v == 0 && tid < NK) cnt[tid] = 0;
    // row = 2048 fp32 = 512 float4; 256 threads * 2 float4 each, coalesced
    const float4* row = (const float4*)(W + (size_t)v * V);
    float4 a = row[tid];
    float4 b = row[tid + 256];
    float s = ((a.x + a.y) + (a.z + a.w)) + ((b.x + b.y) + (b.z + b.w));
    #pragma unroll
    for (int off = 32; off > 0; off >>= 1) s += __shfl_down(s, off, 64);
    if ((tid & 63) == 0) red[tid >> 6] = s;
    __syncthreads();
    if (tid == 0) {
        float deg = (red[0] + red[1]) + (red[2] + red[3]);
        float e = fabsf(deg / fmaxf(1.0f, deg));
        float x = logf(e);
        float sumsq = 0.0f, wv[7];
        #pragma unroll
        for (int j = 2; j <= 8; ++j) {
            float t = x - A_F * (float)(j - 1) * (1.0f / 3.0f);  // R = 3
            float val = 0.0f;
            if (t > -A_F && t <= 0.0f)
                val = 0.5f + 0.5f * cosf(TWO_PI_F * (t / A_F + 0.5f));
            wv[j - 2] = val;
            sumsq += val * val;
        }
        // (R/2)(d0^2+d1^2) + (R/2)d0^2 - sum wav^2 = 1.125 - sumsq
        c[v] = sqrtf(fmaxf(1.125f - sumsq, 0.0f));   // scaling (j index 0)
        #pragma unroll
        for (int j = 0; j < 7; ++j) c[(j + 1) * V + v] = wv[j];
    }
}

// Stage 2: grid (NK branches, NSLICE v-slices) x 128 threads (one per d).
// Branch k: k=0 -> mean of f; k=1..8 -> c_{k-1}*|f|; k>=9 -> c_u*c_j*|f|.
// Partial footprint is only NSLICE*NK*DF = 598 KB (L2-resident). The last
// slice-block per branch (device-scope counter + fences, per G16: per-XCD
// L2s aren't cross-coherent) performs the final 16-way reduction in-place,
// eliminating the separate k_reduce dispatch.
__global__ __launch_bounds__(128) void k_scatter(const float* __restrict__ f,
                                                 const float* __restrict__ c,
                                                 float* __restrict__ part,
                                                 int* __restrict__ cnt,
                                                 float* __restrict__ out) {
    const int k = blockIdx.x;
    const int sl = blockIdx.y;
    const int d = threadIdx.x;
    const int v0 = sl * (V / NSLICE);
    const int v1 = v0 + (V / NSLICE);
    float acc = 0.0f;
    if (k == 0) {
        #pragma unroll 8
        for (int v = v0; v < v1; ++v)
            acc += f[(size_t)v * DF + d];
    } else if (k <= 8) {
        const float* cj = c + (k - 1) * V;
        #pragma unroll 8
        for (int v = v0; v < v1; ++v)
            acc += cj[v] * fabsf(f[(size_t)v * DF + d]);
    } else {
        const float* c1 = c + ((k - 9) >> 3) * V;  // layer-1 branch (u-major)
        const float* c2 = c + ((k - 9) & 7) * V;   // layer-2 filter
        #pragma unroll 8
        for (int v = v0; v < v1; ++v)
            acc += c1[v] * c2[v] * fabsf(f[(size_t)v * DF + d]);
    }
    part[((size_t)sl * NK + k) * DF + d] = acc;

    // ---- last-block-done reduction for this branch k ----
    __threadfence();                    // release: partial visible device-wide
    __shared__ int last;
    if (d == 0) last = (atomicAdd(&cnt[k], 1) == NSLICE - 1);
    __syncthreads();
    if (last) {
        __threadfence();                // acquire: invalidate stale L1 lines
        float s = 0.0f;
        #pragma unroll
        for (int s2 = 0; s2 < NSLICE; ++s2)
            s += part[((size_t)s2 * NK + k) * DF + d];
        out[k * DF + d] = s * (1.0f / (float)V);
    }
}

extern "C" void kernel_launch(void* const* d_in, const int* in_sizes, int n_in,
                              void* d_out, int out_size, void* d_ws, size_t ws_size,
                              hipStream_t stream) {
    const float* W = (const float*)d_in[0];   // fp32 [V,V]
    const float* f = (const float*)d_in[1];   // fp32 [V,DF]
    float* out = (float*)d_out;               // fp32 [NK*DF]

    float* c    = (float*)d_ws;               // 8*V floats = 64 KB
    float* part = c + 8 * V;                  // NSLICE*NK*DF floats = 598 KB
    int*   cnt  = (int*)(part + NSLICE * NK * DF);  // NK counters

    k_filters<<<V, 256, 0, stream>>>(W, c, cnt);
    k_scatter<<<dim3(NK, NSLICE), DF, 0, stream>>>(f, c, part, cnt, out);
}

// Round 7
// 73.209 us; speedup vs baseline: 1.5860x; 1.5860x over previous
//
#include <hip/hip_runtime.h>
#include <math.h>

// Problem constants (hardcoded in reference)
#define V 2048
#define DF 128
#define NK 73          // 1 + J + J^2 branch outputs
#define NSLICE 32      // v-slices per branch (64 rows each) — r6 showed 16.7%
                       // occupancy at 16 slices; 32 doubles TLP, partials
                       // still L2-resident (1.2 MB)
#define A_F 0.34657359027997264f   // A = R*ln(2)/(J-R+1) = ln2/2
#define TWO_PI_F 6.283185307179586f

// Stage 1: one block per node v. deg[v] = rowsum(W), then the J=8 filter
// responses at E = deg/max(1,deg). The reference's Lmat = diag(deg)*dhalf^2
// is EXACTLY diagonal, so eigh is a signed permutation and every filter
// matrix g_j is diag(h_j(deg[v])) — the scattering is pointwise in v.
// 2048 blocks -> 8 blocks/CU: full latency hiding for the 16.8 MB W read.
__global__ __launch_bounds__(256) void k_filters(const float* __restrict__ W,
                                                 float* __restrict__ c) {
    __shared__ float red[4];
    const int v = blockIdx.x;
    const int tid = threadIdx.x;
    // row = 2048 fp32 = 512 float4; 256 threads * 2 float4 each, coalesced
    const float4* row = (const float4*)(W + (size_t)v * V);
    float4 a = row[tid];
    float4 b = row[tid + 256];
    float s = ((a.x + a.y) + (a.z + a.w)) + ((b.x + b.y) + (b.z + b.w));
    #pragma unroll
    for (int off = 32; off > 0; off >>= 1) s += __shfl_down(s, off, 64);
    if ((tid & 63) == 0) red[tid >> 6] = s;
    __syncthreads();
    if (tid == 0) {
        float deg = (red[0] + red[1]) + (red[2] + red[3]);
        float e = fabsf(deg / fmaxf(1.0f, deg));
        float x = logf(e);
        float sumsq = 0.0f, wv[7];
        #pragma unroll
        for (int j = 2; j <= 8; ++j) {
            float t = x - A_F * (float)(j - 1) * (1.0f / 3.0f);  // R = 3
            float val = 0.0f;
            if (t > -A_F && t <= 0.0f)
                val = 0.5f + 0.5f * cosf(TWO_PI_F * (t / A_F + 0.5f));
            wv[j - 2] = val;
            sumsq += val * val;
        }
        // (R/2)(d0^2+d1^2) + (R/2)d0^2 - sum wav^2 = 1.125 - sumsq
        c[v] = sqrtf(fmaxf(1.125f - sumsq, 0.0f));   // scaling (j index 0)
        #pragma unroll
        for (int j = 0; j < 7; ++j) c[(j + 1) * V + v] = wv[j];
    }
}

// Stage 2: grid (NK branches, NSLICE v-slices) x 128 threads (one per d).
// Branch k: k=0 -> mean of f; k=1..8 -> c_{k-1}*|f|; k>=9 -> c_u*c_j*|f|.
// f (1 MB) is L2-resident across the 73 branch re-reads; c loads are
// wave-uniform (scalar-cached). NO fences/atomics — r6 measured the
// device-scope fence pattern at +40 us (L2 wb/inv serialization at TCC).
__global__ __launch_bounds__(128) void k_scatter(const float* __restrict__ f,
                                                 const float* __restrict__ c,
                                                 float* __restrict__ part) {
    const int k = blockIdx.x;
    const int sl = blockIdx.y;
    const int d = threadIdx.x;
    const int v0 = sl * (V / NSLICE);
    const int v1 = v0 + (V / NSLICE);
    float acc = 0.0f;
    if (k == 0) {
        #pragma unroll 16
        for (int v = v0; v < v1; ++v)
            acc += f[(size_t)v * DF + d];
    } else if (k <= 8) {
        const float* cj = c + (k - 1) * V;
        #pragma unroll 16
        for (int v = v0; v < v1; ++v)
            acc += cj[v] * fabsf(f[(size_t)v * DF + d]);
    } else {
        const float* c1 = c + ((k - 9) >> 3) * V;  // layer-1 branch (u-major)
        const float* c2 = c + ((k - 9) & 7) * V;   // layer-2 filter
        #pragma unroll 16
        for (int v = v0; v < v1; ++v)
            acc += c1[v] * c2[v] * fabsf(f[(size_t)v * DF + d]);
    }
    part[((size_t)sl * NK + k) * DF + d] = acc;
}

// Stage 3: sum the NSLICE partials (1.2 MB, L2-resident, coalesced reads),
// apply mean (1/V), write fp32 out.
__global__ __launch_bounds__(256) void k_reduce(const float* __restrict__ part,
                                               float* __restrict__ out) {
    const int i = blockIdx.x * 256 + threadIdx.x;
    if (i < NK * DF) {
        float s = 0.0f;
        #pragma unroll
        for (int sl = 0; sl < NSLICE; ++sl) s += part[(size_t)sl * NK * DF + i];
        out[i] = s * (1.0f / (float)V);
    }
}

extern "C" void kernel_launch(void* const* d_in, const int* in_sizes, int n_in,
                              void* d_out, int out_size, void* d_ws, size_t ws_size,
                              hipStream_t stream) {
    const float* W = (const float*)d_in[0];   // fp32 [V,V]
    const float* f = (const float*)d_in[1];   // fp32 [V,DF]
    float* out = (float*)d_out;               // fp32 [NK*DF]

    float* c    = (float*)d_ws;               // 8*V floats = 64 KB
    float* part = c + 8 * V;                  // NSLICE*NK*DF floats = 1.2 MB

    k_filters<<<V, 256, 0, stream>>>(W, c);
    k_scatter<<<dim3(NK, NSLICE), DF, 0, stream>>>(f, c, part);
    k_reduce<<<(NK * DF + 255) / 256, 256, 0, stream>>>(part, out);
}